// Round 14
// baseline (217.849 us; speedup 1.0000x reference)
//
#include <hip/hip_runtime.h>
#include <hip/hip_bf16.h>

typedef unsigned long long ull;
typedef float nt_float4 __attribute__((ext_vector_type(4)));

#define B_ROWS 32768
#define D_COLS 2048
#define K_SEL  40
#define T_LO   1.74f          // P(x>1.74)=0.0409 -> C ~ 84 +- 9, in [40,128] at ~4.9 sigma
#define CAP    128            // 2 select-slots per lane
#define ALPHA_F  0.01f
#define TARGET_F 0.01953125f  // 40/2048 exact
#define G_COPIES 16           // histogram copies; multiple of 8 => XCD-local atomics

__device__ __forceinline__ ull fkey(float vv, unsigned col) {
    unsigned bits = __float_as_uint(vv);
    unsigned sk = (bits & 0x80000000u) ? ~bits : (bits | 0x80000000u);
    return ((ull)sk << 32) | (ull)(unsigned)(~col);
}

__device__ __forceinline__ float f4elem(const float4& q, int j) {
    return j == 0 ? q.x : j == 1 ? q.y : j == 2 ? q.z : q.w;
}

// pack (val,col) into one 64-bit word: low = val bits, high = col
__device__ __forceinline__ ull pack_pair(float val, unsigned col) {
    return (ull)__float_as_uint(val) | ((ull)col << 32);
}

// Kernel 0: zero the privatized histograms.
__global__ __launch_bounds__(256) void kwta_zero_kernel(uint4* __restrict__ p) {
    p[blockIdx.x * 256 + threadIdx.x] = make_uint4(0u, 0u, 0u, 0u);
}

// ===================== SPLIT PATH (producer/consumer) ======================

// Stream kernel: pure-BW producer. Read row, nt-zero output row, threshold,
// scan, compact candidates to global cand buffer + per-row count. No LDS, no
// radix chains -> waves almost always have memory ops in flight.
__global__ __launch_bounds__(256) void kwta_stream_kernel(
        const float* __restrict__ x, float* __restrict__ out,
        ull* __restrict__ cand, unsigned* __restrict__ cnt_row) {
    const int lane = threadIdx.x & 63;
    const int wid  = threadIdx.x >> 6;
    const int row  = blockIdx.x * 4 + wid;
    const float* xr = x + (size_t)row * D_COLS;
    float* orow = out + (size_t)row * D_COLS;
    const ull lm_lt = (1ull << lane) - 1ull;

    // all 8 row loads in flight
    float4 v[8];
#pragma unroll
    for (int s = 0; s < 8; ++s)
        v[s] = *reinterpret_cast<const float4*>(xr + s * 256 + lane * 4);

    // nt full-row zero issues under load latency (no reuse; spare L3 for x)
    const nt_float4 z = {0.0f, 0.0f, 0.0f, 0.0f};
#pragma unroll
    for (int s = 0; s < 8; ++s)
        __builtin_nontemporal_store(z, reinterpret_cast<nt_float4*>(orow + s * 256) + lane);

    // predicate mask (32 independent compares)
    unsigned m = 0;
#pragma unroll
    for (int s = 0; s < 8; ++s) {
#pragma unroll
        for (int j = 0; j < 4; ++j)
            m |= (f4elem(v[s], j) > T_LO ? 1u : 0u) << (s * 4 + j);
    }
    const unsigned mycnt = __popc(m);

    // bit-plane ballot scan (6 independent ballots)
    unsigned base = 0, C = 0;
#pragma unroll
    for (int b = 0; b < 6; ++b) {
        ull bal = __ballot(((mycnt >> b) & 1u) != 0u);
        base += ((unsigned)__popcll(bal & lm_lt)) << b;
        C    += ((unsigned)__popcll(bal)) << b;
    }

    // predicated compaction to global (order irrelevant; tie-break uses col)
    ull* crow = cand + (size_t)row * CAP;
    unsigned pos = base;
#pragma unroll
    for (int s = 0; s < 8; ++s) {
#pragma unroll
        for (int j = 0; j < 4; ++j) {
            if ((m >> (s * 4 + j)) & 1u) {
                if (pos < CAP)
                    crow[pos] = pack_pair(f4elem(v[s], j),
                                          (unsigned)(s * 256 + lane * 4 + j));
                ++pos;
            }
        }
    }
    if (lane == 0) cnt_row[row] = C;
}

// Select kernel: pure-chain consumer. Reads <=128 candidates coalesced from
// cand (no LDS), exact bitwise radix select, emits 40 packed pairs + counts.
__global__ __launch_bounds__(256) void kwta_select_kernel(
        const float* __restrict__ x, const ull* __restrict__ cand,
        const unsigned* __restrict__ cnt_row, unsigned* __restrict__ cnt,
        ull* __restrict__ pairs) {
    const int lane = threadIdx.x & 63;
    const int wid  = threadIdx.x >> 6;
    const int row  = blockIdx.x * 4 + wid;
    const ull lm_lt = (1ull << lane) - 1ull;
    unsigned* mycnt_arr = cnt + ((size_t)(blockIdx.x & (G_COPIES - 1)) << 11);
    ull* prow = pairs + (size_t)row * K_SEL;
    const unsigned C = cnt_row[row];
    const ull* crow = cand + (size_t)row * CAP;

    if (C >= K_SEL && C <= CAP) {
        const ull q0 = crow[lane];
        const ull q1 = crow[64 + lane];
        const bool ok0 = (unsigned)lane < C;
        const bool ok1 = (unsigned)(64 + lane) < C;
        const float    cv0 = ok0 ? __uint_as_float((unsigned)q0) : 0.0f;
        const float    cv1 = ok1 ? __uint_as_float((unsigned)q1) : 0.0f;
        const unsigned kb0 = __float_as_uint(cv0);  // >1.74 => positive => raw-bit order
        const unsigned kb1 = __float_as_uint(cv1);
        const unsigned cc0 = (unsigned)(q0 >> 32);
        const unsigned cc1 = (unsigned)(q1 >> 32);

        ull a0 = (C >= 64) ? ~0ull : ((1ull << C) - 1ull);
        ull a1 = (C <= 64) ? 0ull : ((C >= 128) ? ~0ull : ((1ull << (C - 64)) - 1ull));
        ull s0 = 0, s1 = 0;
        unsigned kk = K_SEL, na = C;

        if (na == kk) { s0 = a0; s1 = a1; kk = 0; }
        for (int b = 30; b >= 0 && kk; --b) {
            unsigned bit = 1u << b;
            ull b0 = __ballot((kb0 & bit) != 0) & a0;
            ull b1 = __ballot((kb1 & bit) != 0) & a1;
            unsigned cv = (unsigned)__popcll(b0) + (unsigned)__popcll(b1);
            if (cv >= kk) { a0 = b0; a1 = b1; na = cv; }
            else          { s0 |= b0; s1 |= b1; kk -= cv; a0 &= ~b0; a1 &= ~b1; na -= cv; }
            if (na == kk) { s0 |= a0; s1 |= a1; kk = 0; }
        }
        if (kk) {
            // exact ties at threshold: take kk smallest columns
            ull e0 = a0, e1 = a1;
            for (unsigned t = 0; t < kk; ++t) {
                unsigned mymin = 0xFFFFFFFFu;
                if ((e0 >> lane) & 1ull) mymin = min(mymin, cc0);
                if ((e1 >> lane) & 1ull) mymin = min(mymin, cc1);
#pragma unroll
                for (int off = 32; off >= 1; off >>= 1)
                    mymin = min(mymin, (unsigned)__shfl_xor((int)mymin, off, 64));
                bool h0 = ((e0 >> lane) & 1ull) && cc0 == mymin;
                bool h1 = ((e1 >> lane) & 1ull) && cc1 == mymin;
                ull hb0 = __ballot(h0) & e0;
                ull hb1 = __ballot(h1) & e1;
                if (hb0) { s0 |= hb0 & (~hb0 + 1); e0 &= ~(hb0 & (~hb0 + 1)); }
                else     { s1 |= hb1 & (~hb1 + 1); e1 &= ~(hb1 & (~hb1 + 1)); }
            }
        }

        unsigned n0 = (unsigned)__popcll(s0);
        if ((s0 >> lane) & 1ull) {
            unsigned p = (unsigned)__popcll(s0 & lm_lt);
            prow[p] = pack_pair(cv0, cc0);
            atomicAdd(&mycnt_arr[cc0], 1u);
        }
        if ((s1 >> lane) & 1ull) {
            unsigned p = n0 + (unsigned)__popcll(s1 & lm_lt);
            prow[p] = pack_pair(cv1, cc1);
            atomicAdd(&mycnt_arr[cc1], 1u);
        }
    } else {
        // general fallback (statistically never): reload row, K argmax rounds
        const float* xr = x + (size_t)row * D_COLS;
        float4 v[8];
#pragma unroll
        for (int s = 0; s < 8; ++s)
            v[s] = *reinterpret_cast<const float4*>(xr + s * 256 + lane * 4);
        unsigned rm = 0;
        for (int t = 0; t < K_SEL; ++t) {
            ull best = 0;
#pragma unroll
            for (int s = 0; s < 8; ++s) {
#pragma unroll
                for (int j = 0; j < 4; ++j) {
                    int slot = s * 4 + j;
                    if (!((rm >> slot) & 1u)) {
                        ull key = fkey(f4elem(v[s], j), (unsigned)(s * 256 + lane * 4 + j));
                        best = best > key ? best : key;
                    }
                }
            }
#pragma unroll
            for (int off = 32; off >= 1; off >>= 1) {
                ull o = __shfl_xor(best, off, 64);
                best = best > o ? best : o;
            }
#pragma unroll
            for (int s = 0; s < 8; ++s) {
#pragma unroll
                for (int j = 0; j < 4; ++j) {
                    int slot = s * 4 + j;
                    unsigned col = (unsigned)(s * 256 + lane * 4 + j);
                    if (!((rm >> slot) & 1u) && fkey(f4elem(v[s], j), col) == best) {
                        rm |= 1u << slot;
                        prow[t] = pack_pair(f4elem(v[s], j), col);
                        atomicAdd(&mycnt_arr[col], 1u);
                    }
                }
            }
        }
    }
}

// ===================== FUSED/LEGACY FALLBACK (R12 proven) ==================

template <bool FUSED>
__device__ __forceinline__ void process_row(
        const float4 (&v)[8], int row, int lane, float2* __restrict__ my,
        float* __restrict__ out, unsigned* __restrict__ mycnt_arr,
        ull* __restrict__ pairs) {
    const ull lm_lt = (1ull << lane) - 1ull;
    float* orow = out + (size_t)row * D_COLS;
    ull* prow = FUSED ? (pairs + (size_t)row * K_SEL) : nullptr;

    if (FUSED) {
        const nt_float4 z = {0.0f, 0.0f, 0.0f, 0.0f};
#pragma unroll
        for (int s = 0; s < 8; ++s)
            __builtin_nontemporal_store(z, reinterpret_cast<nt_float4*>(orow + s * 256) + lane);
    }

    unsigned m = 0;
#pragma unroll
    for (int s = 0; s < 8; ++s) {
#pragma unroll
        for (int j = 0; j < 4; ++j)
            m |= (f4elem(v[s], j) > T_LO ? 1u : 0u) << (s * 4 + j);
    }
    const unsigned mycnt = __popc(m);

    unsigned base = 0, C = 0;
#pragma unroll
    for (int b = 0; b < 6; ++b) {
        ull bal = __ballot(((mycnt >> b) & 1u) != 0u);
        base += ((unsigned)__popcll(bal & lm_lt)) << b;
        C    += ((unsigned)__popcll(bal)) << b;
    }

    {
        unsigned pos = base;
        const unsigned trash = CAP + (unsigned)lane;
#pragma unroll
        for (int s = 0; s < 8; ++s) {
#pragma unroll
            for (int j = 0; j < 4; ++j) {
                unsigned pred = (m >> (s * 4 + j)) & 1u;
                unsigned dst = pred ? pos : trash;
                dst = min(dst, (unsigned)(CAP + 63));
                my[dst] = make_float2(f4elem(v[s], j),
                    __uint_as_float((unsigned)(s * 256 + lane * 4 + j)));
                pos += pred;
            }
        }
    }

    if (C >= K_SEL && C <= CAP) {
        float2 cd0 = my[lane];
        float2 cd1 = my[64 + lane];
        const bool ok0 = (unsigned)lane < C;
        const bool ok1 = (unsigned)(64 + lane) < C;
        const float    cv0 = ok0 ? cd0.x : 0.0f;
        const float    cv1 = ok1 ? cd1.x : 0.0f;
        const unsigned kb0 = __float_as_uint(cv0);
        const unsigned kb1 = __float_as_uint(cv1);
        const unsigned cc0 = __float_as_uint(cd0.y);
        const unsigned cc1 = __float_as_uint(cd1.y);

        ull a0 = (C >= 64) ? ~0ull : ((1ull << C) - 1ull);
        ull a1 = (C <= 64) ? 0ull : ((C >= 128) ? ~0ull : ((1ull << (C - 64)) - 1ull));
        ull s0 = 0, s1 = 0;
        unsigned kk = K_SEL, na = C;

        if (na == kk) { s0 = a0; s1 = a1; kk = 0; }
        for (int b = 30; b >= 0 && kk; --b) {
            unsigned bit = 1u << b;
            ull b0 = __ballot((kb0 & bit) != 0) & a0;
            ull b1 = __ballot((kb1 & bit) != 0) & a1;
            unsigned cv = (unsigned)__popcll(b0) + (unsigned)__popcll(b1);
            if (cv >= kk) { a0 = b0; a1 = b1; na = cv; }
            else          { s0 |= b0; s1 |= b1; kk -= cv; a0 &= ~b0; a1 &= ~b1; na -= cv; }
            if (na == kk) { s0 |= a0; s1 |= a1; kk = 0; }
        }
        if (kk) {
            ull e0 = a0, e1 = a1;
            for (unsigned t = 0; t < kk; ++t) {
                unsigned mymin = 0xFFFFFFFFu;
                if ((e0 >> lane) & 1ull) mymin = min(mymin, cc0);
                if ((e1 >> lane) & 1ull) mymin = min(mymin, cc1);
#pragma unroll
                for (int off = 32; off >= 1; off >>= 1)
                    mymin = min(mymin, (unsigned)__shfl_xor((int)mymin, off, 64));
                bool h0 = ((e0 >> lane) & 1ull) && cc0 == mymin;
                bool h1 = ((e1 >> lane) & 1ull) && cc1 == mymin;
                ull hb0 = __ballot(h0) & e0;
                ull hb1 = __ballot(h1) & e1;
                if (hb0) { s0 |= hb0 & (~hb0 + 1); e0 &= ~(hb0 & (~hb0 + 1)); }
                else     { s1 |= hb1 & (~hb1 + 1); e1 &= ~(hb1 & (~hb1 + 1)); }
            }
        }

        unsigned n0 = (unsigned)__popcll(s0);
        if ((s0 >> lane) & 1ull) {
            unsigned p = (unsigned)__popcll(s0 & lm_lt);
            if (FUSED) prow[p] = pack_pair(cv0, cc0);
            else       reinterpret_cast<float2*>(orow)[p] = make_float2(cv0, __uint_as_float(cc0));
            atomicAdd(&mycnt_arr[cc0], 1u);
        }
        if ((s1 >> lane) & 1ull) {
            unsigned p = n0 + (unsigned)__popcll(s1 & lm_lt);
            if (FUSED) prow[p] = pack_pair(cv1, cc1);
            else       reinterpret_cast<float2*>(orow)[p] = make_float2(cv1, __uint_as_float(cc1));
            atomicAdd(&mycnt_arr[cc1], 1u);
        }
    } else {
        unsigned rm = 0;
        for (int t = 0; t < K_SEL; ++t) {
            ull best = 0;
#pragma unroll
            for (int s = 0; s < 8; ++s) {
#pragma unroll
                for (int j = 0; j < 4; ++j) {
                    int slot = s * 4 + j;
                    if (!((rm >> slot) & 1u)) {
                        ull key = fkey(f4elem(v[s], j), (unsigned)(s * 256 + lane * 4 + j));
                        best = best > key ? best : key;
                    }
                }
            }
#pragma unroll
            for (int off = 32; off >= 1; off >>= 1) {
                ull o = __shfl_xor(best, off, 64);
                best = best > o ? best : o;
            }
#pragma unroll
            for (int s = 0; s < 8; ++s) {
#pragma unroll
                for (int j = 0; j < 4; ++j) {
                    int slot = s * 4 + j;
                    unsigned col = (unsigned)(s * 256 + lane * 4 + j);
                    if (!((rm >> slot) & 1u) && fkey(f4elem(v[s], j), col) == best) {
                        rm |= 1u << slot;
                        if (FUSED) prow[t] = pack_pair(f4elem(v[s], j), col);
                        else       reinterpret_cast<float2*>(orow)[t] =
                                       make_float2(f4elem(v[s], j), __uint_as_float(col));
                        atomicAdd(&mycnt_arr[col], 1u);
                    }
                }
            }
        }
    }
}

template <bool FUSED>
__global__ __launch_bounds__(256) void kwta_topk_kernel(
        const float* __restrict__ x, float* __restrict__ out,
        unsigned* __restrict__ cnt, ull* __restrict__ pairs) {
    __shared__ float2 cands[4][CAP + 64];
    const int lane = threadIdx.x & 63;
    const int wid  = threadIdx.x >> 6;
    const int row  = blockIdx.x * 4 + wid;
    unsigned* mycnt_arr = cnt + ((size_t)(blockIdx.x & (G_COPIES - 1)) << 11);
    float4 v[8];
#pragma unroll
    for (int s = 0; s < 8; ++s)
        v[s] = *reinterpret_cast<const float4*>(x + (size_t)row * D_COLS + s * 256 + lane * 4);
    process_row<FUSED>(v, row, lane, cands[wid], out, mycnt_arr, pairs);
}

// ========================= epilogue kernels ================================

__global__ __launch_bounds__(128) void kwta_boost_kernel(
        const float* __restrict__ duty, const unsigned* __restrict__ cnt,
        float* __restrict__ boost) {
    int d = blockIdx.x * 128 + threadIdx.x;
    unsigned s = 0;
#pragma unroll
    for (int g = 0; g < G_COPIES; ++g) s += cnt[((size_t)g << 11) + d];
    float mean = (float)s * (1.0f / 32768.0f);
    float nd = duty[d] * (1.0f - ALPHA_F) + ALPHA_F * mean;
    boost[d] = expf(-(nd - TARGET_F));
}

__global__ __launch_bounds__(256) void kwta_fixup_kernel(
        float* __restrict__ out, const ull* __restrict__ pairs,
        const float* __restrict__ boost) {
    const int gid = blockIdx.x * 256 + threadIdx.x;
    const ull pr = pairs[gid];
    const float val = __uint_as_float((unsigned)(pr & 0xFFFFFFFFull));
    const unsigned col = (unsigned)(pr >> 32);
    const int row = gid / K_SEL;
    __builtin_nontemporal_store(val * boost[col], &out[(size_t)row * D_COLS + col]);
}

__global__ __launch_bounds__(256) void kwta_scatter_kernel(
        float* __restrict__ out, const float* __restrict__ boost) {
    __shared__ float buf[D_COLS];
    const int t = threadIdx.x;
    const size_t rb = (size_t)blockIdx.x * D_COLS;
    float2 pr = make_float2(0.0f, 0.0f);
    if (t < K_SEL) pr = reinterpret_cast<const float2*>(out + rb)[t];
    float4 z = make_float4(0.0f, 0.0f, 0.0f, 0.0f);
    reinterpret_cast<float4*>(buf)[t * 2]     = z;
    reinterpret_cast<float4*>(buf)[t * 2 + 1] = z;
    __syncthreads();
    if (t < K_SEL) {
        unsigned col = __float_as_uint(pr.y);
        buf[col] = pr.x * boost[col];
    }
    __syncthreads();
    reinterpret_cast<float4*>(out + rb)[t * 2]     = reinterpret_cast<const float4*>(buf)[t * 2];
    reinterpret_cast<float4*>(out + rb)[t * 2 + 1] = reinterpret_cast<const float4*>(buf)[t * 2 + 1];
}

extern "C" void kernel_launch(void* const* d_in, const int* in_sizes, int n_in,
                              void* d_out, int out_size, void* d_ws, size_t ws_size,
                              hipStream_t stream) {
    const float* x    = (const float*)d_in[0];
    const float* duty = (const float*)d_in[1];
    float* out = (float*)d_out;

    const size_t HIST_BYTES   = (size_t)G_COPIES * 8192;           // 128 KB
    const size_t BOOST_OFF    = HIST_BYTES;                        // 8 KB
    const size_t CNTROW_OFF   = BOOST_OFF + 8192;                  // 128 KB
    const size_t PAIRS_OFF    = CNTROW_OFF + 131072;
    const size_t PAIRS_BYTES  = (size_t)B_ROWS * K_SEL * 8;        // 10.49 MB
    const size_t CAND_OFF     = PAIRS_OFF + PAIRS_BYTES;
    const size_t CAND_BYTES   = (size_t)B_ROWS * CAP * 8;          // 33.55 MB

    unsigned* hist    = (unsigned*)d_ws;
    float*    boost   = (float*)((char*)d_ws + BOOST_OFF);
    unsigned* cnt_row = (unsigned*)((char*)d_ws + CNTROW_OFF);
    ull*      pairs   = (ull*)((char*)d_ws + PAIRS_OFF);
    ull*      cand    = (ull*)((char*)d_ws + CAND_OFF);

    const bool split = ws_size >= CAND_OFF + CAND_BYTES;
    const bool fused = ws_size >= PAIRS_OFF + PAIRS_BYTES;

    kwta_zero_kernel<<<HIST_BYTES / 4096, 256, 0, stream>>>((uint4*)d_ws);

    if (split) {
        kwta_stream_kernel<<<B_ROWS / 4, 256, 0, stream>>>(x, out, cand, cnt_row);
        kwta_select_kernel<<<B_ROWS / 4, 256, 0, stream>>>(x, cand, cnt_row, hist, pairs);
        kwta_boost_kernel<<<D_COLS / 128, 128, 0, stream>>>(duty, hist, boost);
        kwta_fixup_kernel<<<B_ROWS * K_SEL / 256, 256, 0, stream>>>(out, pairs, boost);
    } else if (fused) {
        kwta_topk_kernel<true><<<B_ROWS / 4, 256, 0, stream>>>(x, out, hist, pairs);
        kwta_boost_kernel<<<D_COLS / 128, 128, 0, stream>>>(duty, hist, boost);
        kwta_fixup_kernel<<<B_ROWS * K_SEL / 256, 256, 0, stream>>>(out, pairs, boost);
    } else {
        kwta_topk_kernel<false><<<B_ROWS / 4, 256, 0, stream>>>(x, out, hist, nullptr);
        kwta_boost_kernel<<<D_COLS / 128, 128, 0, stream>>>(duty, hist, boost);
        kwta_scatter_kernel<<<B_ROWS, 256, 0, stream>>>(out, boost);
    }
}

// Round 15
// 172.339 us; speedup vs baseline: 1.2641x; 1.2641x over previous
//
#include <hip/hip_runtime.h>
#include <hip/hip_bf16.h>

typedef unsigned long long ull;
typedef float nt_float4 __attribute__((ext_vector_type(4)));

#define B_ROWS 32768
#define D_COLS 2048
#define K_SEL  40
#define T_LO   1.74f          // P(x>1.74)=0.0409 -> C ~ 84 +- 9, in [40,128] at ~4.9 sigma
#define CAP    128            // 2 select-slots per lane
#define ALPHA_F  0.01f
#define TARGET_F 0.01953125f  // 40/2048 exact
#define G_COPIES 16           // histogram copies; multiple of 8 => XCD-local atomics
#define ROWS_PER_WAVE 4

__device__ __forceinline__ ull fkey(float vv, unsigned col) {
    unsigned bits = __float_as_uint(vv);
    unsigned sk = (bits & 0x80000000u) ? ~bits : (bits | 0x80000000u);
    return ((ull)sk << 32) | (ull)(unsigned)(~col);
}

__device__ __forceinline__ float f4elem(const float4& q, int j) {
    return j == 0 ? q.x : j == 1 ? q.y : j == 2 ? q.z : q.w;
}

__device__ __forceinline__ ull pack_pair(float val, unsigned col) {
    return (ull)__float_as_uint(val) | ((ull)col << 32);
}

__global__ __launch_bounds__(256) void kwta_zero_kernel(uint4* __restrict__ p) {
    p[blockIdx.x * 256 + threadIdx.x] = make_uint4(0u, 0u, 0u, 0u);
}

__device__ __forceinline__ void load_row(float4 (&v)[8], const float* xr, int lane) {
#pragma unroll
    for (int s = 0; s < 8; ++s)
        v[s] = *reinterpret_cast<const float4*>(xr + s * 256 + lane * 4);
}

// ---- per-row select state (2 candidate slots per lane) ----
struct RowSel {
    float cv0, cv1;
    unsigned kb0, kb1, cc0, cc1;
    ull a0, a1, s0, s1;
    unsigned kk, na;
};

__device__ __forceinline__ void init_sel(RowSel& r, const float2* my, unsigned C, int lane) {
    float2 cd0 = my[lane];
    float2 cd1 = my[64 + lane];
    const bool ok0 = (unsigned)lane < C;
    const bool ok1 = (unsigned)(64 + lane) < C;
    r.cv0 = ok0 ? cd0.x : 0.0f;
    r.cv1 = ok1 ? cd1.x : 0.0f;
    r.kb0 = __float_as_uint(r.cv0);   // >1.74 => positive => raw-bit order
    r.kb1 = __float_as_uint(r.cv1);
    r.cc0 = __float_as_uint(cd0.y);
    r.cc1 = __float_as_uint(cd1.y);
    r.a0 = (C >= 64) ? ~0ull : ((1ull << C) - 1ull);
    r.a1 = (C <= 64) ? 0ull : ((C >= 128) ? ~0ull : ((1ull << (C - 64)) - 1ull));
    r.s0 = 0; r.s1 = 0; r.kk = K_SEL; r.na = C;
    if (r.na == r.kk) { r.s0 = r.a0; r.s1 = r.a1; r.kk = 0; }
}

// One radix step. When kk==0 this is a harmless no-op on s0/s1 (cv>=0 always
// takes the 'take' branch which never touches sel) -> no per-row guard needed.
__device__ __forceinline__ void radix_step(RowSel& r, unsigned bit) {
    ull b0 = __ballot((r.kb0 & bit) != 0) & r.a0;
    ull b1 = __ballot((r.kb1 & bit) != 0) & r.a1;
    unsigned cv = (unsigned)__popcll(b0) + (unsigned)__popcll(b1);
    if (cv >= r.kk) { r.a0 = b0; r.a1 = b1; r.na = cv; }
    else { r.s0 |= b0; r.s1 |= b1; r.kk -= cv; r.a0 &= ~b0; r.a1 &= ~b1; r.na -= cv; }
    if (r.kk && r.na == r.kk) { r.s0 |= r.a0; r.s1 |= r.a1; r.kk = 0; }
}

// rare: bits exhausted with ties at threshold -> kk smallest columns
__device__ __forceinline__ void tie_resolve(RowSel& r, int lane) {
    if (!r.kk) return;
    ull e0 = r.a0, e1 = r.a1;
    for (unsigned t = 0; t < r.kk; ++t) {
        unsigned mymin = 0xFFFFFFFFu;
        if ((e0 >> lane) & 1ull) mymin = min(mymin, r.cc0);
        if ((e1 >> lane) & 1ull) mymin = min(mymin, r.cc1);
#pragma unroll
        for (int off = 32; off >= 1; off >>= 1)
            mymin = min(mymin, (unsigned)__shfl_xor((int)mymin, off, 64));
        bool h0 = ((e0 >> lane) & 1ull) && r.cc0 == mymin;
        bool h1 = ((e1 >> lane) & 1ull) && r.cc1 == mymin;
        ull hb0 = __ballot(h0) & e0;
        ull hb1 = __ballot(h1) & e1;
        if (hb0) { r.s0 |= hb0 & (~hb0 + 1); e0 &= ~(hb0 & (~hb0 + 1)); }
        else     { r.s1 |= hb1 & (~hb1 + 1); e1 &= ~(hb1 & (~hb1 + 1)); }
    }
}

template <bool FUSED>
__device__ __forceinline__ void emit_row(const RowSel& r, int lane, ull lm_lt,
        float* orow, ull* prow, unsigned* mycnt_arr) {
    unsigned n0 = (unsigned)__popcll(r.s0);
    if ((r.s0 >> lane) & 1ull) {
        unsigned p = (unsigned)__popcll(r.s0 & lm_lt);
        if (FUSED) __builtin_nontemporal_store(pack_pair(r.cv0, r.cc0), &prow[p]);
        else       reinterpret_cast<float2*>(orow)[p] = make_float2(r.cv0, __uint_as_float(r.cc0));
        atomicAdd(&mycnt_arr[r.cc0], 1u);
    }
    if ((r.s1 >> lane) & 1ull) {
        unsigned p = n0 + (unsigned)__popcll(r.s1 & lm_lt);
        if (FUSED) __builtin_nontemporal_store(pack_pair(r.cv1, r.cc1), &prow[p]);
        else       reinterpret_cast<float2*>(orow)[p] = make_float2(r.cv1, __uint_as_float(r.cc1));
        atomicAdd(&mycnt_arr[r.cc1], 1u);
    }
}

// fully general fallback (statistically never): K argmax rounds over registers
template <bool FUSED>
__device__ __forceinline__ void fallback_row(const float4 (&v)[8], int row, int lane,
        float* orow, ull* prow, unsigned* mycnt_arr) {
    unsigned rm = 0;
    for (int t = 0; t < K_SEL; ++t) {
        ull best = 0;
#pragma unroll
        for (int s = 0; s < 8; ++s) {
#pragma unroll
            for (int j = 0; j < 4; ++j) {
                int slot = s * 4 + j;
                if (!((rm >> slot) & 1u)) {
                    ull key = fkey(f4elem(v[s], j), (unsigned)(s * 256 + lane * 4 + j));
                    best = best > key ? best : key;
                }
            }
        }
#pragma unroll
        for (int off = 32; off >= 1; off >>= 1) {
            ull o = __shfl_xor(best, off, 64);
            best = best > o ? best : o;
        }
#pragma unroll
        for (int s = 0; s < 8; ++s) {
#pragma unroll
            for (int j = 0; j < 4; ++j) {
                int slot = s * 4 + j;
                unsigned col = (unsigned)(s * 256 + lane * 4 + j);
                if (!((rm >> slot) & 1u) && fkey(f4elem(v[s], j), col) == best) {
                    rm |= 1u << slot;
                    if (FUSED) prow[t] = pack_pair(f4elem(v[s], j), col);
                    else       reinterpret_cast<float2*>(orow)[t] =
                                   make_float2(f4elem(v[s], j), __uint_as_float(col));
                    atomicAdd(&mycnt_arr[col], 1u);
                }
            }
        }
    }
}

// stage 1 for one row: zero-write, predicate, ballot-scan, compact to LDS
template <bool FUSED>
__device__ __forceinline__ unsigned stage_row(const float4 (&v)[8], int lane,
        ull lm_lt, float2* my, float* orow) {
    if (FUSED) {
        const nt_float4 z = {0.0f, 0.0f, 0.0f, 0.0f};
#pragma unroll
        for (int s = 0; s < 8; ++s)
            __builtin_nontemporal_store(z, reinterpret_cast<nt_float4*>(orow + s * 256) + lane);
    }
    unsigned m = 0;
#pragma unroll
    for (int s = 0; s < 8; ++s) {
#pragma unroll
        for (int j = 0; j < 4; ++j)
            m |= (f4elem(v[s], j) > T_LO ? 1u : 0u) << (s * 4 + j);
    }
    const unsigned mycnt = __popc(m);
    unsigned base = 0, C = 0;
#pragma unroll
    for (int b = 0; b < 6; ++b) {
        ull bal = __ballot(((mycnt >> b) & 1u) != 0u);
        base += ((unsigned)__popcll(bal & lm_lt)) << b;
        C    += ((unsigned)__popcll(bal)) << b;
    }
    unsigned pos = base;
    const unsigned trash = CAP + (unsigned)lane;
#pragma unroll
    for (int s = 0; s < 8; ++s) {
#pragma unroll
        for (int j = 0; j < 4; ++j) {
            unsigned pred = (m >> (s * 4 + j)) & 1u;
            unsigned dst = pred ? pos : trash;
            dst = min(dst, (unsigned)(CAP + 63));
            my[dst] = make_float2(f4elem(v[s], j),
                __uint_as_float((unsigned)(s * 256 + lane * 4 + j)));
            pos += pred;
        }
    }
    return C;
}

// Process TWO rows: stage both, then run the two radix chains INTERLEAVED in
// one loop — row b's ballot/mask step fills row a's VALU->SALU cross-pipe
// stall bubbles, and loop/branch overhead is halved per row.
template <bool FUSED>
__device__ __forceinline__ void process_pair(
        const float4 (&va)[8], int rowa, const float4 (&vb)[8], int rowb,
        int lane, float2* mya, float2* myb,
        float* __restrict__ out, unsigned* __restrict__ mycnt_arr,
        ull* __restrict__ pairs) {
    const ull lm_lt = (1ull << lane) - 1ull;
    float* orowa = out + (size_t)rowa * D_COLS;
    float* orowb = out + (size_t)rowb * D_COLS;
    ull* prowa = FUSED ? (pairs + (size_t)rowa * K_SEL) : nullptr;
    ull* prowb = FUSED ? (pairs + (size_t)rowb * K_SEL) : nullptr;

    const unsigned Ca = stage_row<FUSED>(va, lane, lm_lt, mya, orowa);
    const unsigned Cb = stage_row<FUSED>(vb, lane, lm_lt, myb, orowb);

    const bool oka = (Ca >= K_SEL && Ca <= CAP);
    const bool okb = (Cb >= K_SEL && Cb <= CAP);

    if (oka && okb) {
        RowSel ra, rb;
        init_sel(ra, mya, Ca, lane);
        init_sel(rb, myb, Cb, lane);
        for (int b = 30; b >= 0; --b) {
            if (!(ra.kk | rb.kk)) break;
            const unsigned bit = 1u << b;
            radix_step(ra, bit);
            radix_step(rb, bit);
        }
        tie_resolve(ra, lane);
        tie_resolve(rb, lane);
        emit_row<FUSED>(ra, lane, lm_lt, orowa, prowa, mycnt_arr);
        emit_row<FUSED>(rb, lane, lm_lt, orowb, prowb, mycnt_arr);
    } else {
        // cold path: handle each row independently
        if (oka) {
            RowSel ra; init_sel(ra, mya, Ca, lane);
            for (int b = 30; b >= 0 && ra.kk; --b) radix_step(ra, 1u << b);
            tie_resolve(ra, lane);
            emit_row<FUSED>(ra, lane, lm_lt, orowa, prowa, mycnt_arr);
        } else {
            fallback_row<FUSED>(va, rowa, lane, orowa, prowa, mycnt_arr);
        }
        if (okb) {
            RowSel rb; init_sel(rb, myb, Cb, lane);
            for (int b = 30; b >= 0 && rb.kk; --b) radix_step(rb, 1u << b);
            tie_resolve(rb, lane);
            emit_row<FUSED>(rb, lane, lm_lt, orowb, prowb, mycnt_arr);
        } else {
            fallback_row<FUSED>(vb, rowb, lane, orowb, prowb, mycnt_arr);
        }
    }
}

// Kernel 1: 4 rows per wave, processed as two dual-selected pairs.
template <bool FUSED>
__global__ __launch_bounds__(256) void kwta_topk_kernel(
        const float* __restrict__ x, float* __restrict__ out,
        unsigned* __restrict__ cnt, ull* __restrict__ pairs) {
    __shared__ float2 cands[4][2][CAP + 64];   // per-wave, two row regions

    const int lane = threadIdx.x & 63;
    const int wid  = threadIdx.x >> 6;
    const int rbase = (blockIdx.x * 4 + wid) * ROWS_PER_WAVE;
    float2* mya = cands[wid][0];
    float2* myb = cands[wid][1];
    unsigned* mycnt_arr = cnt + ((size_t)(blockIdx.x & (G_COPIES - 1)) << 11);

    float4 A[8], B[8];
    load_row(A, x + (size_t)(rbase + 0) * D_COLS, lane);
    load_row(B, x + (size_t)(rbase + 1) * D_COLS, lane);
    process_pair<FUSED>(A, rbase + 0, B, rbase + 1, lane, mya, myb, out, mycnt_arr, pairs);

    load_row(A, x + (size_t)(rbase + 2) * D_COLS, lane);
    load_row(B, x + (size_t)(rbase + 3) * D_COLS, lane);
    process_pair<FUSED>(A, rbase + 2, B, rbase + 3, lane, mya, myb, out, mycnt_arr, pairs);
}

__global__ __launch_bounds__(128) void kwta_boost_kernel(
        const float* __restrict__ duty, const unsigned* __restrict__ cnt,
        float* __restrict__ boost) {
    int d = blockIdx.x * 128 + threadIdx.x;
    unsigned s = 0;
#pragma unroll
    for (int g = 0; g < G_COPIES; ++g) s += cnt[((size_t)g << 11) + d];
    float mean = (float)s * (1.0f / 32768.0f);
    float nd = duty[d] * (1.0f - ALPHA_F) + ALPHA_F * mean;
    boost[d] = expf(-(nd - TARGET_F));
}

__global__ __launch_bounds__(256) void kwta_fixup_kernel(
        float* __restrict__ out, const ull* __restrict__ pairs,
        const float* __restrict__ boost) {
    const int gid = blockIdx.x * 256 + threadIdx.x;
    const ull pr = pairs[gid];
    const float val = __uint_as_float((unsigned)(pr & 0xFFFFFFFFull));
    const unsigned col = (unsigned)(pr >> 32);
    const int row = gid / K_SEL;
    __builtin_nontemporal_store(val * boost[col], &out[(size_t)row * D_COLS + col]);
}

__global__ __launch_bounds__(256) void kwta_scatter_kernel(
        float* __restrict__ out, const float* __restrict__ boost) {
    __shared__ float buf[D_COLS];
    const int t = threadIdx.x;
    const size_t rb = (size_t)blockIdx.x * D_COLS;
    float2 pr = make_float2(0.0f, 0.0f);
    if (t < K_SEL) pr = reinterpret_cast<const float2*>(out + rb)[t];
    float4 z = make_float4(0.0f, 0.0f, 0.0f, 0.0f);
    reinterpret_cast<float4*>(buf)[t * 2]     = z;
    reinterpret_cast<float4*>(buf)[t * 2 + 1] = z;
    __syncthreads();
    if (t < K_SEL) {
        unsigned col = __float_as_uint(pr.y);
        buf[col] = pr.x * boost[col];
    }
    __syncthreads();
    reinterpret_cast<float4*>(out + rb)[t * 2]     = reinterpret_cast<const float4*>(buf)[t * 2];
    reinterpret_cast<float4*>(out + rb)[t * 2 + 1] = reinterpret_cast<const float4*>(buf)[t * 2 + 1];
}

extern "C" void kernel_launch(void* const* d_in, const int* in_sizes, int n_in,
                              void* d_out, int out_size, void* d_ws, size_t ws_size,
                              hipStream_t stream) {
    const float* x    = (const float*)d_in[0];
    const float* duty = (const float*)d_in[1];
    float* out = (float*)d_out;

    const size_t CNT_BYTES   = (size_t)G_COPIES * 8192;          // 128 KB
    const size_t PAIRS_BYTES = (size_t)B_ROWS * K_SEL * 8;       // 10.49 MB

    unsigned* cnt   = (unsigned*)d_ws;
    float*    boost = (float*)((char*)d_ws + CNT_BYTES);
    ull*      pairs = (ull*)((char*)d_ws + CNT_BYTES + 8192);

    const bool fused = ws_size >= CNT_BYTES + 8192 + PAIRS_BYTES;

    kwta_zero_kernel<<<CNT_BYTES / 4096, 256, 0, stream>>>((uint4*)d_ws);

    if (fused) {
        kwta_topk_kernel<true><<<B_ROWS / 4 / ROWS_PER_WAVE, 256, 0, stream>>>(x, out, cnt, pairs);
        kwta_boost_kernel<<<D_COLS / 128, 128, 0, stream>>>(duty, cnt, boost);
        kwta_fixup_kernel<<<B_ROWS * K_SEL / 256, 256, 0, stream>>>(out, pairs, boost);
    } else {
        kwta_topk_kernel<false><<<B_ROWS / 4 / ROWS_PER_WAVE, 256, 0, stream>>>(x, out, cnt, nullptr);
        kwta_boost_kernel<<<D_COLS / 128, 128, 0, stream>>>(duty, cnt, boost);
        kwta_scatter_kernel<<<B_ROWS, 256, 0, stream>>>(out, boost);
    }
}

// Round 16
// 161.957 us; speedup vs baseline: 1.3451x; 1.0641x over previous
//
#include <hip/hip_runtime.h>
#include <hip/hip_bf16.h>

typedef unsigned long long ull;

#define B_ROWS 32768
#define D_COLS 2048
#define K_SEL  40
#define T_LO   1.74f          // P(x>1.74)=0.0409 -> C ~ 84 +- 9, in [40,128] at ~4.9 sigma
#define CAP    128            // 2 select-slots per lane
#define ALPHA_F  0.01f
#define TARGET_F 0.01953125f  // 40/2048 exact
#define G_COPIES 16           // histogram copies; multiple of 8 => XCD-local atomics
#define ROWS_PER_WAVE 4

__device__ __forceinline__ ull fkey(float vv, unsigned col) {
    // monotone (value desc via max, index asc via ~col) 64-bit key
    unsigned bits = __float_as_uint(vv);
    unsigned sk = (bits & 0x80000000u) ? ~bits : (bits | 0x80000000u);
    return ((ull)sk << 32) | (ull)(unsigned)(~col);
}

__device__ __forceinline__ float f4elem(const float4& q, int j) {
    return j == 0 ? q.x : j == 1 ? q.y : j == 2 ? q.z : q.w;
}

// pack (val,col) into one 64-bit word: low = val bits, high = col
__device__ __forceinline__ ull pack_pair(float val, unsigned col) {
    return (ull)__float_as_uint(val) | ((ull)col << 32);
}

// Kernel 0: zero the privatized histograms (rocclr fillBuffer launches a tiny
// grid for small buffers; DIY at full BW).
__global__ __launch_bounds__(256) void kwta_zero_kernel(uint4* __restrict__ p) {
    p[blockIdx.x * 256 + threadIdx.x] = make_uint4(0u, 0u, 0u, 0u);
}

__device__ __forceinline__ void load_row(float4 (&v)[8], const float* xr, int lane) {
#pragma unroll
    for (int s = 0; s < 8; ++s)
        v[s] = *reinterpret_cast<const float4*>(xr + s * 256 + lane * 4);
}

// Process one row already resident in registers: zero-write the output row
// (regular cached stores — nt measured 3.6us slower on this mix, R10 vs R12),
// threshold-compact candidates to wave-private LDS, exact bitwise radix
// select of the top-40, emit packed pairs + histogram counts.
template <bool FUSED>
__device__ __forceinline__ void process_row(
        const float4 (&v)[8], int row, int lane, float2* __restrict__ my,
        float* __restrict__ out, unsigned* __restrict__ mycnt_arr,
        ull* __restrict__ pairs) {
    const ull lm_lt = (1ull << lane) - 1ull;
    float* orow = out + (size_t)row * D_COLS;
    ull* prow = FUSED ? (pairs + (size_t)row * K_SEL) : nullptr;

    if (FUSED) {
        // full-row zero issues under the next row's load latency
        const float4 z = make_float4(0.0f, 0.0f, 0.0f, 0.0f);
#pragma unroll
        for (int s = 0; s < 8; ++s)
            reinterpret_cast<float4*>(orow + s * 256)[lane] = z;
    }

    // ---- per-lane candidate predicate mask (32 independent compares) ----
    unsigned m = 0;
#pragma unroll
    for (int s = 0; s < 8; ++s) {
#pragma unroll
        for (int j = 0; j < 4; ++j)
            m |= (f4elem(v[s], j) > T_LO ? 1u : 0u) << (s * 4 + j);
    }
    const unsigned mycnt = __popc(m);   // [0,32] -> 6 bits

    // ---- bit-plane ballot scan (6 independent ballots) ----
    unsigned base = 0, C = 0;
#pragma unroll
    for (int b = 0; b < 6; ++b) {
        ull bal = __ballot(((mycnt >> b) & 1u) != 0u);
        base += ((unsigned)__popcll(bal & lm_lt)) << b;
        C    += ((unsigned)__popcll(bal)) << b;
    }

    // ---- branchless LDS compaction ----
    {
        unsigned pos = base;
        const unsigned trash = CAP + (unsigned)lane;
#pragma unroll
        for (int s = 0; s < 8; ++s) {
#pragma unroll
            for (int j = 0; j < 4; ++j) {
                unsigned pred = (m >> (s * 4 + j)) & 1u;
                unsigned dst = pred ? pos : trash;
                dst = min(dst, (unsigned)(CAP + 63));
                my[dst] = make_float2(f4elem(v[s], j),
                    __uint_as_float((unsigned)(s * 256 + lane * 4 + j)));
                pos += pred;
            }
        }
    }

    if (C >= K_SEL && C <= CAP) {
        // ---- primary: early-exit bitwise radix select, 2 slots/lane ----
        float2 cd0 = my[lane];
        float2 cd1 = my[64 + lane];
        const bool ok0 = (unsigned)lane < C;
        const bool ok1 = (unsigned)(64 + lane) < C;
        const float    cv0 = ok0 ? cd0.x : 0.0f;
        const float    cv1 = ok1 ? cd1.x : 0.0f;
        const unsigned kb0 = __float_as_uint(cv0);  // >1.74 => positive => raw-bit order
        const unsigned kb1 = __float_as_uint(cv1);
        const unsigned cc0 = __float_as_uint(cd0.y);
        const unsigned cc1 = __float_as_uint(cd1.y);

        ull a0 = (C >= 64) ? ~0ull : ((1ull << C) - 1ull);
        ull a1 = (C <= 64) ? 0ull : ((C >= 128) ? ~0ull : ((1ull << (C - 64)) - 1ull));
        ull s0 = 0, s1 = 0;
        unsigned kk = K_SEL, na = C;

        if (na == kk) { s0 = a0; s1 = a1; kk = 0; }
        for (int b = 30; b >= 0 && kk; --b) {
            unsigned bit = 1u << b;
            ull b0 = __ballot((kb0 & bit) != 0) & a0;
            ull b1 = __ballot((kb1 & bit) != 0) & a1;
            unsigned cv = (unsigned)__popcll(b0) + (unsigned)__popcll(b1);
            if (cv >= kk) { a0 = b0; a1 = b1; na = cv; }
            else          { s0 |= b0; s1 |= b1; kk -= cv; a0 &= ~b0; a1 &= ~b1; na -= cv; }
            if (na == kk) { s0 |= a0; s1 |= a1; kk = 0; }
        }
        if (kk) {
            // bits exhausted: alive are exactly-equal values; take kk smallest cols
            ull e0 = a0, e1 = a1;
            for (unsigned t = 0; t < kk; ++t) {
                unsigned mymin = 0xFFFFFFFFu;
                if ((e0 >> lane) & 1ull) mymin = min(mymin, cc0);
                if ((e1 >> lane) & 1ull) mymin = min(mymin, cc1);
#pragma unroll
                for (int off = 32; off >= 1; off >>= 1)
                    mymin = min(mymin, (unsigned)__shfl_xor((int)mymin, off, 64));
                bool h0 = ((e0 >> lane) & 1ull) && cc0 == mymin;
                bool h1 = ((e1 >> lane) & 1ull) && cc1 == mymin;
                ull hb0 = __ballot(h0) & e0;
                ull hb1 = __ballot(h1) & e1;
                if (hb0) { s0 |= hb0 & (~hb0 + 1); e0 &= ~(hb0 & (~hb0 + 1)); }
                else     { s1 |= hb1 & (~hb1 + 1); e1 &= ~(hb1 & (~hb1 + 1)); }
            }
        }

        // ---- emit 40 packed pairs + counts (XCD-local histogram copy) ----
        unsigned n0 = (unsigned)__popcll(s0);
        if ((s0 >> lane) & 1ull) {
            unsigned p = (unsigned)__popcll(s0 & lm_lt);
            if (FUSED) prow[p] = pack_pair(cv0, cc0);
            else       reinterpret_cast<float2*>(orow)[p] = make_float2(cv0, __uint_as_float(cc0));
            atomicAdd(&mycnt_arr[cc0], 1u);
        }
        if ((s1 >> lane) & 1ull) {
            unsigned p = n0 + (unsigned)__popcll(s1 & lm_lt);
            if (FUSED) prow[p] = pack_pair(cv1, cc1);
            else       reinterpret_cast<float2*>(orow)[p] = make_float2(cv1, __uint_as_float(cc1));
            atomicAdd(&mycnt_arr[cc1], 1u);
        }
    } else {
        // ---- fully general fallback (statistically never for N(0,1) data):
        //      K exact wave-argmax rounds over the in-register row
        unsigned rm = 0;
        for (int t = 0; t < K_SEL; ++t) {
            ull best = 0;
#pragma unroll
            for (int s = 0; s < 8; ++s) {
#pragma unroll
                for (int j = 0; j < 4; ++j) {
                    int slot = s * 4 + j;
                    if (!((rm >> slot) & 1u)) {
                        ull key = fkey(f4elem(v[s], j), (unsigned)(s * 256 + lane * 4 + j));
                        best = best > key ? best : key;
                    }
                }
            }
#pragma unroll
            for (int off = 32; off >= 1; off >>= 1) {
                ull o = __shfl_xor(best, off, 64);
                best = best > o ? best : o;
            }
#pragma unroll
            for (int s = 0; s < 8; ++s) {
#pragma unroll
                for (int j = 0; j < 4; ++j) {
                    int slot = s * 4 + j;
                    unsigned col = (unsigned)(s * 256 + lane * 4 + j);
                    if (!((rm >> slot) & 1u) && fkey(f4elem(v[s], j), col) == best) {
                        rm |= 1u << slot;
                        if (FUSED) prow[t] = pack_pair(f4elem(v[s], j), col);
                        else       reinterpret_cast<float2*>(orow)[t] =
                                       make_float2(f4elem(v[s], j), __uint_as_float(col));
                        atomicAdd(&mycnt_arr[col], 1u);
                    }
                }
            }
        }
    }
}

// Kernel 1: per-row exact top-K, 4 ROWS PER WAVE, software-pipelined: while
// row r's select phase walks its serially-dependent ballot chains, row r+1's
// 8 dwordx4 loads are in flight. Two named register buffers (static indexing).
template <bool FUSED>
__global__ __launch_bounds__(256) void kwta_topk_kernel(
        const float* __restrict__ x, float* __restrict__ out,
        unsigned* __restrict__ cnt, ull* __restrict__ pairs) {
    __shared__ float2 cands[4][CAP + 64];   // per-wave region (+64 trash slots)

    const int lane = threadIdx.x & 63;
    const int wid  = threadIdx.x >> 6;
    const int rbase = (blockIdx.x * 4 + wid) * ROWS_PER_WAVE;
    float2* my = cands[wid];
    unsigned* mycnt_arr = cnt + ((size_t)(blockIdx.x & (G_COPIES - 1)) << 11);

    float4 A[8], B[8];
    load_row(A, x + (size_t)(rbase + 0) * D_COLS, lane);

    load_row(B, x + (size_t)(rbase + 1) * D_COLS, lane);      // prefetch r1
    process_row<FUSED>(A, rbase + 0, lane, my, out, mycnt_arr, pairs);

    load_row(A, x + (size_t)(rbase + 2) * D_COLS, lane);      // prefetch r2
    process_row<FUSED>(B, rbase + 1, lane, my, out, mycnt_arr, pairs);

    load_row(B, x + (size_t)(rbase + 3) * D_COLS, lane);      // prefetch r3
    process_row<FUSED>(A, rbase + 2, lane, my, out, mycnt_arr, pairs);

    process_row<FUSED>(B, rbase + 3, lane, my, out, mycnt_arr, pairs);
}

// Kernel 2: sum 16 histogram copies; boost[d] = exp(-(duty*0.99 + 0.01*cnt/B
// - target)). 16 blocks x 128 threads: readers spread over all XCDs.
__global__ __launch_bounds__(128) void kwta_boost_kernel(
        const float* __restrict__ duty, const unsigned* __restrict__ cnt,
        float* __restrict__ boost) {
    int d = blockIdx.x * 128 + threadIdx.x;
    unsigned s = 0;
#pragma unroll
    for (int g = 0; g < G_COPIES; ++g) s += cnt[((size_t)g << 11) + d];
    float mean = (float)s * (1.0f / 32768.0f);
    float nd = duty[d] * (1.0f - ALPHA_F) + ALPHA_F * mean;
    boost[d] = expf(-(nd - TARGET_F));
}

// Kernel 3 (fused path): one thread per (row,k) pair — overwrite the selected
// slot with val*boost[col]. Regular cached accesses (nt measured slower).
__global__ __launch_bounds__(256) void kwta_fixup_kernel(
        float* __restrict__ out, const ull* __restrict__ pairs,
        const float* __restrict__ boost) {
    const int gid = blockIdx.x * 256 + threadIdx.x;
    const ull pr = pairs[gid];
    const float val = __uint_as_float((unsigned)(pr & 0xFFFFFFFFull));
    const unsigned col = (unsigned)(pr >> 32);
    const int row = gid / K_SEL;
    out[(size_t)row * D_COLS + col] = val * boost[col];
}

// Kernel 3 (legacy path): block-per-row scatter via LDS (used only if ws_size
// can't hold the pairs buffer).
__global__ __launch_bounds__(256) void kwta_scatter_kernel(
        float* __restrict__ out, const float* __restrict__ boost) {
    __shared__ float buf[D_COLS];
    const int t = threadIdx.x;
    const size_t rb = (size_t)blockIdx.x * D_COLS;

    float2 pr = make_float2(0.0f, 0.0f);
    if (t < K_SEL) pr = reinterpret_cast<const float2*>(out + rb)[t];

    float4 z = make_float4(0.0f, 0.0f, 0.0f, 0.0f);
    reinterpret_cast<float4*>(buf)[t * 2]     = z;
    reinterpret_cast<float4*>(buf)[t * 2 + 1] = z;
    __syncthreads();

    if (t < K_SEL) {
        unsigned col = __float_as_uint(pr.y);
        buf[col] = pr.x * boost[col];
    }
    __syncthreads();

    reinterpret_cast<float4*>(out + rb)[t * 2]     = reinterpret_cast<const float4*>(buf)[t * 2];
    reinterpret_cast<float4*>(out + rb)[t * 2 + 1] = reinterpret_cast<const float4*>(buf)[t * 2 + 1];
}

extern "C" void kernel_launch(void* const* d_in, const int* in_sizes, int n_in,
                              void* d_out, int out_size, void* d_ws, size_t ws_size,
                              hipStream_t stream) {
    const float* x    = (const float*)d_in[0];
    const float* duty = (const float*)d_in[1];
    float* out = (float*)d_out;

    const size_t CNT_BYTES   = (size_t)G_COPIES * 8192;          // 128 KB
    const size_t PAIRS_BYTES = (size_t)B_ROWS * K_SEL * 8;       // 10.49 MB

    unsigned* cnt   = (unsigned*)d_ws;
    float*    boost = (float*)((char*)d_ws + CNT_BYTES);
    ull*      pairs = (ull*)((char*)d_ws + CNT_BYTES + 8192);

    const bool fused = ws_size >= CNT_BYTES + 8192 + PAIRS_BYTES;

    kwta_zero_kernel<<<CNT_BYTES / 4096, 256, 0, stream>>>((uint4*)d_ws);

    if (fused) {
        kwta_topk_kernel<true><<<B_ROWS / 4 / ROWS_PER_WAVE, 256, 0, stream>>>(x, out, cnt, pairs);
        kwta_boost_kernel<<<D_COLS / 128, 128, 0, stream>>>(duty, cnt, boost);
        kwta_fixup_kernel<<<B_ROWS * K_SEL / 256, 256, 0, stream>>>(out, pairs, boost);
    } else {
        kwta_topk_kernel<false><<<B_ROWS / 4 / ROWS_PER_WAVE, 256, 0, stream>>>(x, out, cnt, nullptr);
        kwta_boost_kernel<<<D_COLS / 128, 128, 0, stream>>>(duty, cnt, boost);
        kwta_scatter_kernel<<<B_ROWS, 256, 0, stream>>>(out, boost);
    }
}